// Round 9
// baseline (189.252 us; speedup 1.0000x reference)
//
#include <hip/hip_runtime.h>
#include <hip/hip_bf16.h>

// SelfAttentionHead: B=4, S=4096, D=256, fp32 in/out.
// out = qp + softmax(tril_mul(qp kp^T / 16)) @ vp, masked entries enter softmax as 0.
// R9: 8-wave (512-thr) blocks, 256 q-rows, KVBLK=64, D-split (each block computes 128 of
// 256 output dims; QK redundant), 5-bit K swizzle (conflict-free QK reads), counted-vmcnt
// double-buffered staging, 6-way split-K + queue balance, exp2-space softmax, combine6.

typedef __bf16 bf16x8 __attribute__((ext_vector_type(8)));
typedef float f32x4 __attribute__((ext_vector_type(4)));
typedef float f32x16 __attribute__((ext_vector_type(16)));
typedef unsigned int u32x4 __attribute__((ext_vector_type(4)));

#define MASKV -3.0e38f

__device__ __forceinline__ unsigned short f2bf_u(float f) {
  unsigned u = __float_as_uint(f);
  u += 0x7fffu + ((u >> 16) & 1u);
  return (unsigned short)(u >> 16);
}
__device__ __forceinline__ float bf2f(unsigned u16) {
  return __uint_as_float(u16 << 16);
}
__device__ __forceinline__ unsigned short cvt_bf(float f) {
  return __builtin_bit_cast(unsigned short, (__bf16)f);
}

// ---------------- WT[j][k] = bf16(W[k][j]) ----------------
__global__ __launch_bounds__(256) void wt_kernel(
    const float* __restrict__ Wq, const float* __restrict__ Wk, const float* __restrict__ Wv,
    unsigned short* __restrict__ WTq, unsigned short* __restrict__ WTk, unsigned short* __restrict__ WTv) {
  int j = blockIdx.x & 255;
  int wsel = blockIdx.x >> 8;
  const float* W = wsel == 0 ? Wq : (wsel == 1 ? Wk : Wv);
  unsigned short* WT = wsel == 0 ? WTq : (wsel == 1 ? WTk : WTv);
  int k = threadIdx.x;
  WT[j * 256 + k] = f2bf_u(W[k * 256 + j]);
}

// ---------------- Fused projection GEMMs: grid (256, 3) ----------------
__global__ __launch_bounds__(256) void proj_all_kernel(
    const float* __restrict__ q_in, const float* __restrict__ k_in, const float* __restrict__ v_in,
    const unsigned short* __restrict__ WTq, const unsigned short* __restrict__ WTk,
    const unsigned short* __restrict__ WTv,
    const float* __restrict__ bq, const float* __restrict__ bk, const float* __restrict__ bv,
    unsigned short* __restrict__ qpb, unsigned short* __restrict__ kpb,
    float* __restrict__ vpf, unsigned short* __restrict__ vptb) {
  int mode = blockIdx.y;
  const float* X = mode == 0 ? q_in : (mode == 1 ? k_in : v_in);
  const unsigned short* WT = mode == 0 ? WTq : (mode == 1 ? WTk : WTv);
  const float* bias = mode == 0 ? bq : (mode == 1 ? bk : bv);

  int rt = blockIdx.x;
  int tid = threadIdx.x;
  int w = tid >> 6, l = tid & 63, g = l >> 4, lm = l & 15;
  int arow = rt * 64 + w * 16 + lm;

  f32x4 acc[16];
#pragma unroll
  for (int i = 0; i < 16; i++) acc[i] = (f32x4){0.f, 0.f, 0.f, 0.f};

#pragma unroll
  for (int kb = 0; kb < 256; kb += 32) {
    const float* ap = X + arow * 256 + kb + 8 * g;
    float4 a0 = *(const float4*)ap;
    float4 a1 = *(const float4*)(ap + 4);
    bf16x8 af;
    af[0] = (__bf16)a0.x; af[1] = (__bf16)a0.y; af[2] = (__bf16)a0.z; af[3] = (__bf16)a0.w;
    af[4] = (__bf16)a1.x; af[5] = (__bf16)a1.y; af[6] = (__bf16)a1.z; af[7] = (__bf16)a1.w;
#pragma unroll
    for (int nt = 0; nt < 16; nt++) {
      bf16x8 bf = *(const bf16x8*)(WT + (nt * 16 + lm) * 256 + kb + 8 * g);
      acc[nt] = __builtin_amdgcn_mfma_f32_16x16x32_bf16(af, bf, acc[nt], 0, 0, 0);
    }
  }

#pragma unroll
  for (int nt = 0; nt < 16; nt++) {
    int col = nt * 16 + lm;
    float bb = bias[col];
#pragma unroll
    for (int r = 0; r < 4; r++) {
      int orow = rt * 64 + w * 16 + 4 * g + r;
      float v = acc[nt][r] + bb;
      int idx = orow * 256 + col;
      if (mode == 0) {
        qpb[idx] = f2bf_u(v * 0.0625f);  // bf16(qp/16): lossless pow2, residual = 16*bf2f
      } else if (mode == 1) {
        kpb[idx] = f2bf_u(v * 1.4426950408889634f);  // fold log2e -> scores in log2 space
      } else {
        vpf[idx] = v;
        int b = orow >> 12, sidx = orow & 4095;
        // tiled: vptb[b][kt=sidx>>6][d=col][kk=sidx&63]
        vptb[(((size_t)b * 64 + (sidx >> 6)) * 256 + col) * 64 + (sidx & 63)] = f2bf_u(v);
      }
    }
  }
}

// ---------------- Suffix-sum of vp (exclusive), 64-row chunks; suffv stored bf16 ----------------
__global__ __launch_bounds__(256) void scan1(const float* __restrict__ vpf, float* __restrict__ ctot) {
  int c = blockIdx.x, b = blockIdx.y, d = threadIdx.x;
  const float* base = vpf + (b * 4096 + c * 64) * 256 + d;
  float acc = 0.f;
#pragma unroll 4
  for (int r = 0; r < 64; r++) acc += base[r * 256];
  ctot[(b * 64 + c) * 256 + d] = acc;
}

__global__ __launch_bounds__(256) void scan2(const float* __restrict__ vpf, const float* __restrict__ ctot,
                                             unsigned short* __restrict__ suffv) {
  int c = blockIdx.x, b = blockIdx.y, d = threadIdx.x;
  float acc = 0.f;
  for (int c2 = c + 1; c2 < 64; c2++) acc += ctot[(b * 64 + c2) * 256 + d];
  const float* base = vpf + (b * 4096 + c * 64) * 256 + d;
  unsigned short* sbase = suffv + (b * 4096 + c * 64) * 256 + d;
  for (int r = 63; r >= 0; r--) {
    sbase[r * 256] = f2bf_u(acc);
    acc += base[r * 256];
  }
}

// ---------------- Flash attention: 8 waves, 256 q-rows, KVBLK=64, D-split ----------------
// 768 blocks x 512 threads. bid&7: b=(bid&7)>>1, shi=bid&1 (k-half -> s in 0..2 / 3..5).
// j=bid>>3 in [0,96): dh=j&1 (output-dim half), v=j>>1: qt=15-v/3 (big-first), s=shi*3+v%3.
// k-tiles (64 keys) [s*NT/6,(s+1)*NT/6), NT=4(qt+1). LDS 96KB: K[2][64][256] (5-bit swz) +
// Vhalf[2][128][64] (3-bit swz). Both dh blocks compute QK redundantly; PV/O only own half.
__global__ __launch_bounds__(512, 2) void attn9_kernel(
    const unsigned short* __restrict__ qpb, const unsigned short* __restrict__ kpb,
    const unsigned short* __restrict__ vptb,
    unsigned short* __restrict__ slot01,  // d_out, row-interleaved [grow][s][256]
    unsigned short* __restrict__ slot23,  // [s-2][grow][256]
    unsigned short* __restrict__ slot45,  // [s-4][grow][256]
    float* __restrict__ mz) {             // [s][m/Z][16384]
  extern __shared__ char smem[];

  int bid = blockIdx.x;
  int low = bid & 7;
  int b = low >> 1, shi = low & 1;
  int j = bid >> 3;
  int dh = j & 1;
  int v = j >> 1;
  int vd3 = v / 3;
  int qt = 15 - vd3;
  int s = shi * 3 + (v - vd3 * 3);
  int NT = 4 * (qt + 1);
  int t0 = (s * NT) / 6, t1 = ((s + 1) * NT) / 6;

  int tid = threadIdx.x;
  int wv = tid >> 6, l = tid & 63;
  int hi = l >> 5, r32 = l & 31;
  int vsw = r32 & 7;  // V read swizzle (3-bit)

  int qwave = qt * 256 + 32 * wv;
  int qglob = qwave + r32;

  // Q as B-fragments (col = lane&31 = q-row), pre-scaled by 1/16 (log2e folded into K)
  bf16x8 qf[16];
  const unsigned short* qsrc = qpb + (size_t)(b * 4096 + qwave + r32) * 256;
#pragma unroll
  for (int st = 0; st < 16; st++) qf[st] = *(const bf16x8*)(qsrc + st * 16 + 8 * hi);

  f32x16 zero16;
#pragma unroll
  for (int ee = 0; ee < 16; ee++) zero16[ee] = 0.f;
  f32x16 O[4];
#pragma unroll
  for (int dt = 0; dt < 4; dt++) O[dt] = zero16;
  float m_ = -1e30f, Z_ = 0.f;

  const unsigned short* kbase0 = kpb + (size_t)b * 4096 * 256;
  const unsigned short* vbase0 = vptb + (size_t)b * 64 * 256 * 64 + (size_t)dh * 128 * 64;

  // stage one 64-key tile: K 32KB (4 chunks/thread, 5-bit swz) + Vhalf 16KB (2 chunks, 3-bit swz)
  auto STAGE = [&](int bi, int kt) {
    char* Kdst = smem + bi * 32768;
    char* Vdst = smem + 65536 + bi * 16384;
    const unsigned short* ksrc = kbase0 + (size_t)kt * 64 * 256;
    const unsigned short* vtile = vbase0 + (size_t)kt * 256 * 64;
#pragma unroll
    for (int i = 0; i < 4; i++) {
      int ch = i * 512 + tid;
      int row = ch >> 5, cc = ch & 31;
      __builtin_amdgcn_global_load_lds(
          (const __attribute__((address_space(1))) unsigned int*)(ksrc + row * 256 + ((cc ^ (row & 31)) * 8)),
          (__attribute__((address_space(3))) unsigned int*)(Kdst + ch * 16), 16, 0, 0);
    }
#pragma unroll
    for (int i = 0; i < 2; i++) {
      int ch = i * 512 + tid;
      int dl = ch >> 3, cs = ch & 7;
      __builtin_amdgcn_global_load_lds(
          (const __attribute__((address_space(1))) unsigned int*)(vtile + dl * 64 + ((cs ^ (dl & 7)) * 8)),
          (__attribute__((address_space(3))) unsigned int*)(Vdst + ch * 16), 16, 0, 0);
    }
  };

  if (t0 < t1) {
    STAGE(0, t0);
    if (t0 + 1 < t1) STAGE(1, t0 + 1);
  }

  for (int kt = t0; kt < t1; kt++) {
    int cur = (kt - t0) & 1;
    int kb2 = kt * 64;

    if (kt + 1 < t1) asm volatile("s_waitcnt vmcnt(6)" ::: "memory");
    else             asm volatile("s_waitcnt vmcnt(0)" ::: "memory");
    __builtin_amdgcn_s_barrier();
    __builtin_amdgcn_sched_barrier(0);

    if (kb2 <= qwave + 31) {  // wave not fully masked
      const char* Kp = smem + cur * 32768;
      const char* Vp = smem + 65536 + cur * 16384;

      // ---- QK^T (swapped): St[key][q] log2-space; keys kb2+{0..31} -> St0, +{32..63} -> St1
      f32x16 St0, St1;
      __builtin_amdgcn_s_setprio(1);
      {
        bf16x8 kf0 = *(const bf16x8*)(Kp + r32 * 512 + ((hi ^ r32) & 31) * 16);
        bf16x8 kf1 = *(const bf16x8*)(Kp + (32 + r32) * 512 + ((hi ^ r32) & 31) * 16);
        St0 = __builtin_amdgcn_mfma_f32_32x32x16_bf16(kf0, qf[0], zero16, 0, 0, 0);
        St1 = __builtin_amdgcn_mfma_f32_32x32x16_bf16(kf1, qf[0], zero16, 0, 0, 0);
      }
#pragma unroll
      for (int st = 1; st < 16; st++) {
        int cc = ((2 * st + hi) ^ r32) & 31;
        bf16x8 kf0 = *(const bf16x8*)(Kp + r32 * 512 + cc * 16);
        bf16x8 kf1 = *(const bf16x8*)(Kp + (32 + r32) * 512 + cc * 16);
        St0 = __builtin_amdgcn_mfma_f32_32x32x16_bf16(kf0, qf[st], St0, 0, 0, 0);
        St1 = __builtin_amdgcn_mfma_f32_32x32x16_bf16(kf1, qf[st], St1, 0, 0, 0);
      }
      __builtin_amdgcn_s_setprio(0);

      // ---- causal mask (wave-uniform guard) ----
      if (kb2 + 63 > qwave) {
#pragma unroll
        for (int r = 0; r < 16; r++) {
          int kg = kb2 + (r & 3) + 8 * (r >> 2) + 4 * hi;
          if (kg > qglob) St0[r] = MASKV;
          if (kg + 32 > qglob) St1[r] = MASKV;
        }
      }

      // ---- in-register online softmax over 64 keys (exp2 space) ----
      float mx = fmaxf(St0[0], St1[0]);
#pragma unroll
      for (int r = 1; r < 16; r++) mx = fmaxf(mx, fmaxf(St0[r], St1[r]));
      mx = fmaxf(mx, __shfl_xor(mx, 32));
      bool upd = __any(mx > m_ + 8.f);
      if (upd) {
        float mn = fmaxf(m_, mx);
        float scl = exp2f(m_ - mn);
        m_ = mn;
        Z_ *= scl;
#pragma unroll
        for (int r = 0; r < 16; r++) {
          int qr = (r & 3) + 8 * (r >> 2) + 4 * hi;
          float sb = __uint_as_float(
              (unsigned)__builtin_amdgcn_ds_bpermute(qr * 4, (int)__float_as_uint(scl)));
#pragma unroll
          for (int dt = 0; dt < 4; dt++) O[dt][r] *= sb;
        }
      }
      float rs = 0.f;
#pragma unroll
      for (int r = 0; r < 16; r++) {
        St0[r] = exp2f(St0[r] - m_);
        St1[r] = exp2f(St1[r] - m_);
        rs += St0[r] + St1[r];
      }
      rs += __shfl_xor(rs, 32);
      Z_ += rs;

      // ---- sub0: pack P(keys 0..31) -> pa0,pa1; PV ks=0,1 ----
      {
        unsigned X0 = (unsigned)cvt_bf(St0[0]) | ((unsigned)cvt_bf(St0[1]) << 16);
        unsigned X1 = (unsigned)cvt_bf(St0[2]) | ((unsigned)cvt_bf(St0[3]) << 16);
        unsigned X2 = (unsigned)cvt_bf(St0[4]) | ((unsigned)cvt_bf(St0[5]) << 16);
        unsigned X3 = (unsigned)cvt_bf(St0[6]) | ((unsigned)cvt_bf(St0[7]) << 16);
        unsigned X4 = (unsigned)cvt_bf(St0[8]) | ((unsigned)cvt_bf(St0[9]) << 16);
        unsigned X5 = (unsigned)cvt_bf(St0[10]) | ((unsigned)cvt_bf(St0[11]) << 16);
        unsigned X6 = (unsigned)cvt_bf(St0[12]) | ((unsigned)cvt_bf(St0[13]) << 16);
        unsigned X7 = (unsigned)cvt_bf(St0[14]) | ((unsigned)cvt_bf(St0[15]) << 16);
        unsigned Y0 = (unsigned)__shfl_xor((int)X0, 32);
        unsigned Y1 = (unsigned)__shfl_xor((int)X1, 32);
        unsigned Y2 = (unsigned)__shfl_xor((int)X2, 32);
        unsigned Y3 = (unsigned)__shfl_xor((int)X3, 32);
        unsigned Y4 = (unsigned)__shfl_xor((int)X4, 32);
        unsigned Y5 = (unsigned)__shfl_xor((int)X5, 32);
        unsigned Y6 = (unsigned)__shfl_xor((int)X6, 32);
        unsigned Y7 = (unsigned)__shfl_xor((int)X7, 32);
        u32x4 A0, A1;
        A0[0] = hi ? Y2 : X0; A0[1] = hi ? Y3 : X1;
        A0[2] = hi ? X2 : Y0; A0[3] = hi ? X3 : Y1;
        A1[0] = hi ? Y6 : X4; A1[1] = hi ? Y7 : X5;
        A1[2] = hi ? X6 : Y4; A1[3] = hi ? X7 : Y5;
        bf16x8 pa0 = __builtin_bit_cast(bf16x8, A0);
        bf16x8 pa1 = __builtin_bit_cast(bf16x8, A1);
        __builtin_amdgcn_s_setprio(1);
#pragma unroll
        for (int dt = 0; dt < 4; dt++) {
          const char* vrow = Vp + (dt * 32 + r32) * 128;
          bf16x8 vf0 = *(const bf16x8*)(vrow + ((hi ^ vsw) * 16));
          O[dt] = __builtin_amdgcn_mfma_f32_32x32x16_bf16(pa0, vf0, O[dt], 0, 0, 0);
          bf16x8 vf1 = *(const bf16x8*)(vrow + (((2 + hi) ^ vsw) * 16));
          O[dt] = __builtin_amdgcn_mfma_f32_32x32x16_bf16(pa1, vf1, O[dt], 0, 0, 0);
        }
        __builtin_amdgcn_s_setprio(0);
      }
      // ---- sub1: pack P(keys 32..63) -> pa2,pa3; PV ks=2,3 ----
      {
        unsigned X0 = (unsigned)cvt_bf(St1[0]) | ((unsigned)cvt_bf(St1[1]) << 16);
        unsigned X1 = (unsigned)cvt_bf(St1[2]) | ((unsigned)cvt_bf(St1[3]) << 16);
        unsigned X2 = (unsigned)cvt_bf(St1[4]) | ((unsigned)cvt_bf(St1[5]) << 16);
        unsigned X3 = (unsigned)cvt_bf(St1[6]) | ((unsigned)cvt_bf(St1[7]) << 16);
        unsigned X4 = (unsigned)cvt_bf(St1[8]) | ((unsigned)cvt_bf(St1[9]) << 16);
        unsigned X5 = (unsigned)cvt_bf(St1[10]) | ((unsigned)cvt_bf(St1[11]) << 16);
        unsigned X6 = (unsigned)cvt_bf(St1[12]) | ((unsigned)cvt_bf(St1[13]) << 16);
        unsigned X7 = (unsigned)cvt_bf(St1[14]) | ((unsigned)cvt_bf(St1[15]) << 16);
        unsigned Y0 = (unsigned)__shfl_xor((int)X0, 32);
        unsigned Y1 = (unsigned)__shfl_xor((int)X1, 32);
        unsigned Y2 = (unsigned)__shfl_xor((int)X2, 32);
        unsigned Y3 = (unsigned)__shfl_xor((int)X3, 32);
        unsigned Y4 = (unsigned)__shfl_xor((int)X4, 32);
        unsigned Y5 = (unsigned)__shfl_xor((int)X5, 32);
        unsigned Y6 = (unsigned)__shfl_xor((int)X6, 32);
        unsigned Y7 = (unsigned)__shfl_xor((int)X7, 32);
        u32x4 A2, A3;
        A2[0] = hi ? Y2 : X0; A2[1] = hi ? Y3 : X1;
        A2[2] = hi ? X2 : Y0; A2[3] = hi ? X3 : Y1;
        A3[0] = hi ? Y6 : X4; A3[1] = hi ? Y7 : X5;
        A3[2] = hi ? X6 : Y4; A3[3] = hi ? X7 : Y5;
        bf16x8 pa2 = __builtin_bit_cast(bf16x8, A2);
        bf16x8 pa3 = __builtin_bit_cast(bf16x8, A3);
        __builtin_amdgcn_s_setprio(1);
#pragma unroll
        for (int dt = 0; dt < 4; dt++) {
          const char* vrow = Vp + (dt * 32 + r32) * 128;
          bf16x8 vf2 = *(const bf16x8*)(vrow + (((4 + hi) ^ vsw) * 16));
          O[dt] = __builtin_amdgcn_mfma_f32_32x32x16_bf16(pa2, vf2, O[dt], 0, 0, 0);
          bf16x8 vf3 = *(const bf16x8*)(vrow + (((6 + hi) ^ vsw) * 16));
          O[dt] = __builtin_amdgcn_mfma_f32_32x32x16_bf16(pa3, vf3, O[dt], 0, 0, 0);
        }
        __builtin_amdgcn_s_setprio(0);
      }
    }

    __builtin_amdgcn_sched_barrier(0);
    __builtin_amdgcn_s_barrier();
    if (kt + 2 < t1) STAGE(cur, kt + 2);
  }

  // ---- write partial stats + bf16 O (half-width columns) ----
  int grow_base = b * 4096 + qwave;
  if (dh == 0 && hi == 0) {
    float* mzm = mz + s * 32768;
    mzm[grow_base + r32] = m_;
    mzm[16384 + grow_base + r32] = Z_;
  }
#pragma unroll
  for (int r = 0; r < 16; r++) {
    int qr = (r & 3) + 8 * (r >> 2) + 4 * hi;
    size_t grow = (size_t)(grow_base + qr);
#pragma unroll
    for (int dt = 0; dt < 4; dt++) {
      int dcol = dh * 128 + dt * 32 + r32;
      unsigned short vb = cvt_bf(O[dt][r]);
      if (s < 2)
        slot01[grow * 512 + (size_t)s * 256 + dcol] = vb;
      else if (s < 4)
        slot23[(size_t)(s - 2) * 4194304 + grow * 256 + dcol] = vb;
      else
        slot45[(size_t)(s - 4) * 4194304 + grow * 256 + dcol] = vb;
    }
  }
}

// ---------------- combine6: merge 6 partials + masked-zero correction + qp residual ----------------
__global__ __launch_bounds__(256) void combine6_kernel(
    const float* __restrict__ mz,
    const unsigned short* __restrict__ slot23, const unsigned short* __restrict__ slot45,
    const unsigned short* __restrict__ qpb, const unsigned short* __restrict__ suffv,
    float* __restrict__ out) {
  int grow = blockIdx.x * 4 + (threadIdx.x >> 6);
  int col = (threadIdx.x & 63) * 4;
  const unsigned short* slot01 = (const unsigned short*)out;

  float mv[6], Zv[6];
#pragma unroll
  for (int s = 0; s < 6; s++) {
    const float* mzm = mz + s * 32768;
    mv[s] = mzm[grow];
    Zv[s] = mzm[16384 + grow];
  }
  float M = mv[0];
#pragma unroll
  for (int s = 1; s < 6; s++) M = fmaxf(M, mv[s]);
  float fs[6], Zm = 0.f;
#pragma unroll
  for (int s = 0; s < 6; s++) {
    fs[s] = exp2f(mv[s] - M);
    Zm += Zv[s] * fs[s];
  }

  int q = grow & 4095;
  int nmask = 4095 - q;
  float scl, e0, Zf;
  if (nmask > 0) {
    float Mf = fmaxf(M, 0.f);  // log2-space: masked zeros contribute 2^(0 - Mf)
    scl = exp2f(M - Mf);
    e0 = exp2f(-Mf);
    Zf = Zm * scl + (float)nmask * e0;
  } else {
    scl = 1.f; e0 = 0.f; Zf = Zm;
  }
  float rZ = 1.f / Zf;
  float a[6];
#pragma unroll
  for (int s = 0; s < 6; s++) a[s] = fs[s] * scl * rZ;
  float asv = e0 * rZ;

  size_t base = (size_t)grow * 256 + col;
  uint2 ss[6];
  ss[0] = *(const uint2*)(slot01 + (size_t)grow * 512 + col);
  ss[1] = *(const uint2*)(slot01 + (size_t)grow * 512 + 256 + col);
  ss[2] = *(const uint2*)(slot23 + base);
  ss[3] = *(const uint2*)(slot23 + 4194304 + base);
  ss[4] = *(const uint2*)(slot45 + base);
  ss[5] = *(const uint2*)(slot45 + 4194304 + base);
  uint2 qpr = *(const uint2*)(qpb + base);
  uint2 svu = *(const uint2*)(suffv + base);

  __syncthreads();  // all slot01 (= out bytes) reads in this block complete before writes

  float4 res;
  res.x = 16.f * bf2f(qpr.x & 0xffff) + bf2f(svu.x & 0xffff) * asv;
  res.y = 16.f * bf2f(qpr.x >> 16) + bf2f(svu.x >> 16) * asv;
  res.z = 16.f * bf2f(qpr.y & 0xffff) + bf2f(svu.y & 0xffff) * asv;
  res.w = 16.f * bf2f(qpr.y >> 16) + bf2f(svu.y >> 16) * asv;
#pragma unroll
  for (int s = 0; s < 6; s++) {
    res.x += bf2f(ss[s].x & 0xffff) * a[s];
    res.y += bf2f(ss[s].x >> 16) * a[s];
    res.z += bf2f(ss[s].y & 0xffff) * a[s];
    res.w += bf2f(ss[s].y >> 16) * a[s];
  }
  *(float4*)&out[base] = res;
}

// ---------------- launch ----------------
// Workspace layout (disjoint; ~65.4 MiB):
//   [ 0,16M) slot45 | [16M,32M) vpf->slot23 | [32M,40M) suffv bf16 | [40M,48M) qpb
//   [48M,56M) kpb | [56M,64M) vptb [B][64][256][64] | [64M,+768K) mz | then WT / ctot
extern "C" void kernel_launch(void* const* d_in, const int* in_sizes, int n_in,
                              void* d_out, int out_size, void* d_ws, size_t ws_size,
                              hipStream_t stream) {
  const float* v_in = (const float*)d_in[0];
  const float* k_in = (const float*)d_in[1];
  const float* q_in = (const float*)d_in[2];
  const float* Wq = (const float*)d_in[3];
  const float* bq = (const float*)d_in[4];
  const float* Wk = (const float*)d_in[5];
  const float* bk = (const float*)d_in[6];
  const float* Wv = (const float*)d_in[7];
  const float* bv = (const float*)d_in[8];
  float* out = (float*)d_out;

  char* p = (char*)d_ws;
  unsigned short* slot45 = (unsigned short*)(p + 0);
  float* vpf = (float*)(p + 16777216);
  unsigned short* slot23 = (unsigned short*)(p + 16777216);
  unsigned short* suffv = (unsigned short*)(p + 33554432);
  unsigned short* qpb = (unsigned short*)(p + 41943040);
  unsigned short* kpb = (unsigned short*)(p + 50331648);
  unsigned short* vptb = (unsigned short*)(p + 58720256);
  float* mz = (float*)(p + 67108864);
  unsigned short* WTq = (unsigned short*)(p + 67895296);
  unsigned short* WTk = (unsigned short*)(p + 68026368);
  unsigned short* WTv = (unsigned short*)(p + 68157440);
  float* ctot = (float*)(p + 68288512);
  unsigned short* slot01 = (unsigned short*)d_out;

  hipFuncSetAttribute((const void*)attn9_kernel,
                      hipFuncAttributeMaxDynamicSharedMemorySize, 98304);

  wt_kernel<<<768, 256, 0, stream>>>(Wq, Wk, Wv, WTq, WTk, WTv);
  proj_all_kernel<<<dim3(256, 3), 256, 0, stream>>>(q_in, k_in, v_in, WTq, WTk, WTv,
                                                    bq, bk, bv, qpb, kpb, vpf, vptb);
  scan1<<<dim3(64, 4), 256, 0, stream>>>(vpf, ctot);
  scan2<<<dim3(64, 4), 256, 0, stream>>>(vpf, ctot, suffv);
  attn9_kernel<<<768, 512, 98304, stream>>>(qpb, kpb, vptb, slot01, slot23, slot45, mz);
  combine6_kernel<<<4096, 256, 0, stream>>>(mz, slot23, slot45, qpb, suffv, out);
}